// Round 5
// baseline (2744.269 us; speedup 1.0000x reference)
//
#include <hip/hip_runtime.h>
#include <math.h>

// SPDNet forward, one wave (64 lanes) per batch element.
// One-sided (Hestenes) Jacobi with hypercube/xor pair ordering, columns
// fully register-resident. Partner columns fetched via ds_bpermute (no LDS
// round-trip, no barriers); dot reductions via DPP quad_perm (VALU pipe).
// Rotation updates use bit-symmetric expression forms (fp contract off) so
// the two redundant owner-quads stay bit-identical.
//
// jac32: quad q owns cols {2q,2q+1} (rows 8s..8s+7 per lane, 2 f4 each).
//        Sweep = intra rotation + 15 xor-masks x 4 cross rotations.
// jac16: quad q owns col q (rows 4s..4s+3, 1 f4). Sweep = 15 masks x 1 rot.

#define MAXSW32 10
#define MAXSW16 9
#define MAXSW4  8
#define JTOL2   1e-12f

typedef float f4 __attribute__((ext_vector_type(4)));

__device__ __forceinline__ float hsum(f4 v) { return (v.x + v.y) + (v.z + v.w); }

__device__ __forceinline__ float qsum(float d) {
  d += __int_as_float(__builtin_amdgcn_mov_dpp(__float_as_int(d), 0xB1, 0xF, 0xF, true)); // xor1
  d += __int_as_float(__builtin_amdgcn_mov_dpp(__float_as_int(d), 0x4E, 0xF, 0xF, true)); // xor2
  return d;
}
__device__ __forceinline__ float bpermf(int pidx, float v) {
  return __int_as_float(__builtin_amdgcn_ds_bpermute(pidx, __float_as_int(v)));
}
__device__ __forceinline__ f4 bperm4(int pidx, f4 v) {
  f4 r;
  r.x = bpermf(pidx, v.x); r.y = bpermf(pidx, v.y);
  r.z = bpermf(pidx, v.z); r.w = bpermf(pidx, v.w);
  return r;
}

// Jacobi rotation params from off-diag dot d and norms. Divide-free; exactly
// antisymmetric under (na<->nb): returns (c, -s).
__device__ __forceinline__ void rot_cs(float d, float na, float nb,
                                       float& c, float& s) {
  float tau = 0.5f * (nb - na);
  float r   = __builtin_amdgcn_sqrtf(fmaf(tau, tau, d * d));
  float den = fabsf(tau) + r;
  float tnum = __uint_as_float(__float_as_uint(d) ^
                               (__float_as_uint(tau) & 0x80000000u));
  float t = tnum * __builtin_amdgcn_rcpf(den);
  c = __builtin_amdgcn_rsqf(fmaf(t, t, 1.f));
  s = t * c;
}

// Rotate register column pair (a,b) with norms na,nb. Bit-symmetric under
// role swap (a<->b): both owner quads compute identical updates.
__device__ __forceinline__ bool rot_pair(f4& a0, f4& a1, f4& b0, f4& b1,
                                         float& na, float& nb) {
  f4 d4 = a0 * b0 + a1 * b1;
  float d = qsum(hsum(d4));
  bool act = (d * d > JTOL2 * (na * nb));
  if (act) {
    float c, s;
    rot_cs(d, na, nb, c, s);
    {
#pragma clang fp contract(off)
      f4 pa0 = a0 * c, pb0 = b0 * s, qa0 = a0 * s, qb0 = b0 * c;
      f4 pa1 = a1 * c, pb1 = b1 * s, qa1 = a1 * s, qb1 = b1 * c;
      a0 = pa0 - pb0; b0 = qa0 + qb0;
      a1 = pa1 - pb1; b1 = qa1 + qb1;
      float cc = c * c, ss = s * s, cs2 = (2.f * c) * s * d;
      float t0 = cc * na, t1 = ss * nb, t2 = ss * na, t3 = cc * nb;
      float nna = (t0 + t1) - cs2;
      nb = (t2 + t3) + cs2;
      na = nna;
    }
  }
  return act;
}
// Same for a single f4 column (n=16 case); updates own column only.
__device__ __forceinline__ bool rot_one(f4& a, f4 b, float& na, float nb) {
  f4 d4 = a * b;
  float d = qsum(hsum(d4));
  bool act = (d * d > JTOL2 * (na * nb));
  if (act) {
    float c, s;
    rot_cs(d, na, nb, c, s);
    {
#pragma clang fp contract(off)
      f4 pa = a * c, pb = b * s;
      a = pa - pb;
      float cc = c * c, ss = s * s, cs2 = (2.f * c) * s * d;
      na = (cc * na + ss * nb) - cs2;
    }
  }
  return act;
}

__launch_bounds__(64)
__global__ void spdnet_kernel(const float* __restrict__ x,
                              const float* __restrict__ w1,
                              const float* __restrict__ w2,
                              const float* __restrict__ w3,
                              const float* __restrict__ fcw,
                              float* __restrict__ out,
                              int B) {
  const int b    = blockIdx.x;
  const int lane = threadIdx.x;

  // R0: x -> L -> X1 (cols, stride 36) -> [free] -> M2(320) + w3@512(80)
  //     + Y@640(64) + X3@704(16)
  // R1: w1 (rows, stride 36) -> w2 col-major [0..576) + Z @576 (32x20)
  __shared__ __attribute__((aligned(16))) float R0[1152];
  __shared__ __attribute__((aligned(16))) float R1[1216];

  const float* xb = x + (size_t)b * 1024;
  const int kc = lane >> 1, h = lane & 1, hb = h * 16;
  const int q = lane >> 2, s = lane & 3;

  // ---- stage x -> R0, w1 -> R1 (row-major, stride 36); prefetch w2/w3 ----
  float w2r[8];
  #pragma unroll
  for (int t = 0; t < 8; ++t) w2r[t] = w2[lane + 64 * t];
  float w3r = w3[lane];
  #pragma unroll
  for (int t = 0; t < 4; ++t) {
    int i4 = lane + 64 * t;
    int r = i4 >> 3, c4 = i4 & 7;
    *(f4*)(R0 + r * 36 + 4 * c4) = ((const f4*)xb)[i4];
    *(f4*)(R1 + r * 36 + 4 * c4) = ((const f4*)w1)[i4];
  }
  __syncthreads();

  // ---- L = x * w1 : lane (kc,h) computes col kc rows hb..hb+15 ----
  f4 a0 = {0, 0, 0, 0}, a1 = a0, a2 = a0, a3 = a0;
  #pragma unroll
  for (int j = 0; j < 32; ++j) {
    float wv = R1[j * 36 + kc];
    const float* xc = R0 + j * 36 + hb;
    a0 += (*(const f4*)(xc)) * wv;
    a1 += (*(const f4*)(xc + 4)) * wv;
    a2 += (*(const f4*)(xc + 8)) * wv;
    a3 += (*(const f4*)(xc + 12)) * wv;
  }
  __syncthreads();
  *(f4*)(R0 + kc * 36 + hb)      = a0;
  *(f4*)(R0 + kc * 36 + hb + 4)  = a1;
  *(f4*)(R0 + kc * 36 + hb + 8)  = a2;
  *(f4*)(R0 + kc * 36 + hb + 12) = a3;
  __syncthreads();

  // ---- X1[:,kc] = sum_k w1[k][:] * L[k][kc] ----
  float Lc[32];
  #pragma unroll
  for (int c4 = 0; c4 < 8; ++c4) {
    f4 v = *(const f4*)(R0 + kc * 36 + 4 * c4);
    Lc[4 * c4] = v.x; Lc[4 * c4 + 1] = v.y; Lc[4 * c4 + 2] = v.z; Lc[4 * c4 + 3] = v.w;
  }
  a0 = (f4){0, 0, 0, 0}; a1 = a0; a2 = a0; a3 = a0;
  #pragma unroll
  for (int kk = 0; kk < 32; ++kk) {
    float lv = Lc[kk];
    const float* wr = R1 + kk * 36 + hb;
    a0 += (*(const f4*)(wr)) * lv;
    a1 += (*(const f4*)(wr + 4)) * lv;
    a2 += (*(const f4*)(wr + 8)) * lv;
    a3 += (*(const f4*)(wr + 12)) * lv;
  }
  __syncthreads();
  *(f4*)(R0 + kc * 36 + hb)      = a0;
  *(f4*)(R0 + kc * 36 + hb + 4)  = a1;
  *(f4*)(R0 + kc * 36 + hb + 8)  = a2;
  *(f4*)(R0 + kc * 36 + hb + 12) = a3;
  // stage w2 col-major over dead w1
  #pragma unroll
  for (int t = 0; t < 8; ++t) {
    int idx = lane + 64 * t;
    int j = idx >> 4, a = idx & 15;
    R1[a * 36 + j] = w2r[t];
  }
  __syncthreads();

  // ---- load X1 cols into registers: quad q owns cols 2q, 2q+1 ----
  const float* c0p = R0 + (2 * q) * 36 + 8 * s;
  f4 g0a = *(const f4*)(c0p),      g0b = *(const f4*)(c0p + 4);
  f4 g1a = *(const f4*)(c0p + 36), g1b = *(const f4*)(c0p + 40);
  float n0 = qsum(hsum(g0a * g0a + g0b * g0b));
  float n1 = qsum(hsum(g1a * g1a + g1b * g1b));

  // ---- eig #1: register-resident one-sided Jacobi, n=32 ----
  for (int sw = 0; sw < MAXSW32; ++sw) {
    bool anyact = rot_pair(g0a, g0b, g1a, g1b, n0, n1);  // intra
    for (int m = 1; m < 16; ++m) {
      int pidx = ((lane ^ (m << 2)) << 2);
      f4 h0a = bperm4(pidx, g0a), h0b = bperm4(pidx, g0b);
      f4 h1a = bperm4(pidx, g1a), h1b = bperm4(pidx, g1b);
      float m0 = bpermf(pidx, n0), m1 = bpermf(pidx, n1);
      bool r1 = rot_pair(g0a, g0b, h0a, h0b, n0, m0);
      bool r2 = rot_pair(g1a, g1b, h1a, h1b, n1, m1);
      bool r3 = rot_pair(g0a, g0b, h1a, h1b, n0, m1);  // disjoint from r4
      bool r4 = rot_pair(g1a, g1b, h0a, h0b, n1, m0);
      anyact |= (r1 | r2 | r3 | r4);
    }
    if (__ballot(anyact) == 0ull) break;
  }

  // ---- exact norms; Z[:,c] = (w2^T g_c) * sqrt(mu)/lam directly from regs ----
  n0 = qsum(hsum(g0a * g0a + g0b * g0b));
  n1 = qsum(hsum(g1a * g1a + g1b * g1b));
  float lam0 = __builtin_amdgcn_sqrtf(n0);
  float lam1 = __builtin_amdgcn_sqrtf(n1);
  float sc0 = __builtin_amdgcn_sqrtf(fmaxf(lam0, 1e-4f)) *
              __builtin_amdgcn_rcpf(fmaxf(lam0, 1e-30f));
  float sc1 = __builtin_amdgcn_sqrtf(fmaxf(lam1, 1e-4f)) *
              __builtin_amdgcn_rcpf(fmaxf(lam1, 1e-30f));
  #pragma unroll
  for (int a = 0; a < 16; ++a) {
    f4 wva = *(const f4*)(R1 + a * 36 + 8 * s);       // broadcast across quads
    f4 wvb = *(const f4*)(R1 + a * 36 + 8 * s + 4);
    float t0 = qsum(hsum(g0a * wva + g0b * wvb));
    float t1 = qsum(hsum(g1a * wva + g1b * wvb));
    float zv = (s == 0) ? t0 * sc0 : t1 * sc1;
    if (s < 2) R1[576 + (2 * q + s) * 20 + a] = zv;
  }
  __syncthreads();

  // ---- M2 = Z Z^T (16x16) into R0 col-major stride 20; stage w3 ----
  {
    const int a = lane & 15, b0i = (lane >> 4) * 4;
    f4 m4 = {0, 0, 0, 0};
    #pragma unroll
    for (int kk = 0; kk < 32; ++kk) {
      float za = R1[576 + kk * 20 + a];
      f4 zb = *(const f4*)(R1 + 576 + kk * 20 + b0i);
      m4 += zb * za;
    }
    R0[(b0i + 0) * 20 + a] = m4.x;
    R0[(b0i + 1) * 20 + a] = m4.y;
    R0[(b0i + 2) * 20 + a] = m4.z;
    R0[(b0i + 3) * 20 + a] = m4.w;
    R0[512 + (lane & 3) * 20 + (lane >> 2)] = w3r;  // w3 col-major stride 20
  }
  __syncthreads();

  // ---- eig #2: register-resident one-sided Jacobi, n=16 (col per quad) ----
  f4 g2 = *(const f4*)(R0 + q * 20 + 4 * s);
  float n2 = qsum(hsum(g2 * g2));
  for (int sw = 0; sw < MAXSW16; ++sw) {
    bool anyact = false;
    for (int m = 1; m < 16; ++m) {
      int pidx = ((lane ^ (m << 2)) << 2);
      f4 hcol = bperm4(pidx, g2);
      float nb = bpermf(pidx, n2);
      anyact |= rot_one(g2, hcol, n2, nb);
    }
    if (__ballot(anyact) == 0ull) break;
  }

  // ---- Y[a][k] = (w3_col_a . g2_k) * sqrt(mu2)/lam2 ----
  n2 = qsum(hsum(g2 * g2));
  {
    float lam2 = __builtin_amdgcn_sqrtf(n2);
    float sc2  = __builtin_amdgcn_sqrtf(fmaxf(lam2, 1e-4f)) *
                 __builtin_amdgcn_rcpf(fmaxf(lam2, 1e-30f));
    float yv[4];
    #pragma unroll
    for (int a = 0; a < 4; ++a) {
      f4 wv = *(const f4*)(R0 + 512 + a * 20 + 4 * s);
      yv[a] = qsum(hsum(g2 * wv)) * sc2;
    }
    R0[640 + q * 4 + s] = yv[s];   // Y k-major stride 4 (all 64 lanes)
  }
  __syncthreads();
  if (lane < 16) {
    int a = lane >> 2, b2 = lane & 3;
    float sacc = 0.f;
    #pragma unroll
    for (int kk = 0; kk < 16; ++kk)
      sacc += R0[640 + kk * 4 + a] * R0[640 + kk * 4 + b2];
    R0[704 + lane] = sacc;         // X3
  }
  __syncthreads();

  // ---- stage 3: serial 4x4 two-sided Jacobi + LogEig + fc + log_softmax ----
  if (lane == 0) {
    float Am[4][4], V[4][4];
    float maxd = 0.f;
    #pragma unroll
    for (int i = 0; i < 4; ++i) {
      #pragma unroll
      for (int j = 0; j < 4; ++j) {
        Am[i][j] = R0[704 + i * 4 + j];
        V[i][j] = (i == j) ? 1.f : 0.f;
      }
      maxd = fmaxf(maxd, fabsf(Am[i][i]));
    }
    float tol3 = 1e-7f * maxd;
    for (int sw = 0; sw < MAXSW4; ++sw) {
      bool any = false;
      #pragma unroll
      for (int p = 0; p < 3; ++p) {
        #pragma unroll
        for (int qq2 = p + 1; qq2 < 4; ++qq2) {
          float apq = Am[p][qq2];
          if (fabsf(apq) > tol3) {
            any = true;
            float c, sv;
            rot_cs(apq, Am[p][p], Am[qq2][qq2], c, sv);
            #pragma unroll
            for (int j = 0; j < 4; ++j) {
              float ap = Am[p][j], aq = Am[qq2][j];
              Am[p][j] = c * ap - sv * aq;
              Am[qq2][j] = sv * ap + c * aq;
            }
            #pragma unroll
            for (int i = 0; i < 4; ++i) {
              float ap = Am[i][p], aq = Am[i][qq2];
              Am[i][p] = c * ap - sv * aq;
              Am[i][qq2] = sv * ap + c * aq;
              float up = V[i][p], uq = V[i][qq2];
              V[i][p] = c * up - sv * uq;
              V[i][qq2] = sv * up + c * uq;
            }
          }
        }
      }
      if (!any) break;
    }
    float lm[4];
    #pragma unroll
    for (int i = 0; i < 4; ++i) lm[i] = logf(fmaxf(Am[i][i], 1e-10f));
    float feat[16];
    #pragma unroll
    for (int i = 0; i < 4; ++i)
      #pragma unroll
      for (int j = 0; j < 4; ++j) {
        float acc2 = 0.f;
        #pragma unroll
        for (int kk = 0; kk < 4; ++kk) acc2 += V[i][kk] * lm[kk] * V[j][kk];
        feat[i * 4 + j] = acc2;
      }
    float z0 = 0.f, z1 = 0.f;
    #pragma unroll
    for (int f = 0; f < 16; ++f) {
      z0 += feat[f] * fcw[f * 2 + 0];
      z1 += feat[f] * fcw[f * 2 + 1];
    }
    float mx = fmaxf(z0, z1);
    float lse = mx + logf(expf(z0 - mx) + expf(z1 - mx));
    out[b * 2 + 0] = z0 - lse;
    out[b * 2 + 1] = z1 - lse;
    float* fo = out + (size_t)2 * B + (size_t)b * 16;
    #pragma unroll
    for (int f = 0; f < 16; ++f) fo[f] = feat[f];
  }
}

extern "C" void kernel_launch(void* const* d_in, const int* in_sizes, int n_in,
                              void* d_out, int out_size, void* d_ws, size_t ws_size,
                              hipStream_t stream) {
  (void)n_in; (void)d_ws; (void)ws_size; (void)out_size;
  const float* x   = (const float*)d_in[0];
  const float* w1  = (const float*)d_in[1];
  const float* w2  = (const float*)d_in[2];
  const float* w3  = (const float*)d_in[3];
  const float* fcw = (const float*)d_in[4];
  float* out = (float*)d_out;
  int B = in_sizes[0] / 1024;
  spdnet_kernel<<<B, 64, 0, stream>>>(x, w1, w2, w3, fcw, out, B);
}

// Round 7
// 2232.252 us; speedup vs baseline: 1.2294x; 1.2294x over previous
//
#include <hip/hip_runtime.h>
#include <math.h>

// SPDNet forward, one wave (64 lanes) per batch element, one-sided (Hestenes)
// Jacobi. Columns orthogonalized in place in LDS; eigenvalues = column norms,
// eigenvectors = normalized columns. All column traffic ds_read/write_b128.
// Rotations use the divide-free form t = sign(tau)*d / (|tau|+sqrt(tau^2+d^2))
// with raw v_rcp/v_rsq/v_sqrt (no IEEE div/sqrt fixup sequences).
//
// KEY (round 7): block = 1 wave, so LDS ops are hardware-ordered (per-wave
// FIFO at the LDS unit). The per-round __syncthreads() of round 4 is replaced
// by a compiler-only fence: next round's ds_reads may ISSUE before the prior
// round's writes complete (HW returns post-write data), removing the
// lgkmcnt(0) drain per round and letting rounds pipeline.
//
// LDS: R0[1152] matrix buffer (stride 36 / 20), R1[1216] weights+Z, NRM[32].
// ~9.6 KB/wave -> ~16 waves/CU.

#define MAXSW32 8
#define MAXSW16 8
#define MAXSW4  8
#define JTOL2   1e-12f

// Compiler-only memory fence: prevents reordering of LDS accesses across
// rounds without emitting s_waitcnt/s_barrier (single-wave correctness).
#define CFENCE() asm volatile("" ::: "memory")

__device__ __forceinline__ float shfl_xor_f(float v, int m) { return __shfl_xor(v, m, 64); }
__device__ __forceinline__ float dot4(float4 a, float4 b) {
  return a.x * b.x + a.y * b.y + a.z * b.z + a.w * b.w;
}
__device__ __forceinline__ void axpy4(float4& a, float xv, float4 w) {
  a.x += xv * w.x; a.y += xv * w.y; a.z += xv * w.z; a.w += xv * w.w;
}
// Jacobi rotation from off-diag dot d and norms dpp,dqq. Divide-free.
__device__ __forceinline__ void rot_cs(float d, float dpp, float dqq,
                                       float& c, float& s) {
  float tau = 0.5f * (dqq - dpp);
  float r   = __builtin_amdgcn_sqrtf(fmaf(tau, tau, d * d));
  float den = fabsf(tau) + r;
  float tnum = __uint_as_float(__float_as_uint(d) ^
                               (__float_as_uint(tau) & 0x80000000u));
  float t = tnum * __builtin_amdgcn_rcpf(den);
  c = __builtin_amdgcn_rsqf(fmaf(t, t, 1.f));
  s = t * c;
}

// One-sided Jacobi, n=32, column stride 36. 16 pairs x 4 lanes.
__device__ __forceinline__ void jac32(float* __restrict__ G, float* __restrict__ nrm,
                                      int lane) {
  const int k = lane >> 2, sub = lane & 3;
  const int o0 = 4 * sub, o1 = 4 * sub + 16;
  int pp = (k == 0) ? 31 : k;
  int qq = (k == 0) ? 0 : (31 - k);
  for (int sw = 0; sw < MAXSW32; ++sw) {
    bool anyact = false;
    for (int r = 0; r < 31; ++r) {
      CFENCE();                       // order vs previous round's LDS writes
      const int p = pp, q = qq;
      if (k != 0) { pp += 16; if (pp >= 31) pp -= 31; }
      qq += 16; if (qq >= 31) qq -= 31;
      const int pb = p * 36, qb = q * 36;
      float dpp = nrm[p], dqq = nrm[q];
      float4 gp0 = *(const float4*)(G + pb + o0);
      float4 gp1 = *(const float4*)(G + pb + o1);
      float4 gq0 = *(const float4*)(G + qb + o0);
      float4 gq1 = *(const float4*)(G + qb + o1);
      float d = dot4(gp0, gq0) + dot4(gp1, gq1);
      d += shfl_xor_f(d, 1);
      d += shfl_xor_f(d, 2);
      bool active = (d * d > JTOL2 * dpp * dqq);
      if (__ballot(active) == 0ull) continue;
      anyact = true;
      if (active) {
        float c, s;
        rot_cs(d, dpp, dqq, c, s);
        float4 np0, np1, nq0, nq1;
        np0.x = c * gp0.x - s * gq0.x; nq0.x = s * gp0.x + c * gq0.x;
        np0.y = c * gp0.y - s * gq0.y; nq0.y = s * gp0.y + c * gq0.y;
        np0.z = c * gp0.z - s * gq0.z; nq0.z = s * gp0.z + c * gq0.z;
        np0.w = c * gp0.w - s * gq0.w; nq0.w = s * gp0.w + c * gq0.w;
        np1.x = c * gp1.x - s * gq1.x; nq1.x = s * gp1.x + c * gq1.x;
        np1.y = c * gp1.y - s * gq1.y; nq1.y = s * gp1.y + c * gq1.y;
        np1.z = c * gp1.z - s * gq1.z; nq1.z = s * gp1.z + c * gq1.z;
        np1.w = c * gp1.w - s * gq1.w; nq1.w = s * gp1.w + c * gq1.w;
        *(float4*)(G + pb + o0) = np0;
        *(float4*)(G + pb + o1) = np1;
        *(float4*)(G + qb + o0) = nq0;
        *(float4*)(G + qb + o1) = nq1;
        if (sub == 0) {
          float cs2 = 2.f * c * s * d, cc = c * c, ss = s * s;
          nrm[p] = cc * dpp - cs2 + ss * dqq;
          nrm[q] = ss * dpp + cs2 + cc * dqq;
        }
      }
    }
    if (!anyact) break;
  }
  __syncthreads();
}

// One-sided Jacobi, n=16, column stride 20. 8 pairs x 8 lanes.
__device__ __forceinline__ void jac16(float* __restrict__ G, float* __restrict__ nrm,
                                      int lane) {
  const int k = lane >> 3, sub = lane & 7;
  const int o = 2 * sub;
  int pp = (k == 0) ? 15 : k;
  int qq = (k == 0) ? 0 : (15 - k);
  for (int sw = 0; sw < MAXSW16; ++sw) {
    bool anyact = false;
    for (int r = 0; r < 15; ++r) {
      CFENCE();
      const int p = pp, q = qq;
      if (k != 0) { pp += 8; if (pp >= 15) pp -= 15; }
      qq += 8; if (qq >= 15) qq -= 15;
      const int pb = p * 20 + o, qb = q * 20 + o;
      float dpp = nrm[p], dqq = nrm[q];
      float2 gp = *(const float2*)(G + pb);
      float2 gq = *(const float2*)(G + qb);
      float d = gp.x * gq.x + gp.y * gq.y;
      d += shfl_xor_f(d, 1);
      d += shfl_xor_f(d, 2);
      d += shfl_xor_f(d, 4);
      bool active = (d * d > JTOL2 * dpp * dqq);
      if (__ballot(active) == 0ull) continue;
      anyact = true;
      if (active) {
        float c, s;
        rot_cs(d, dpp, dqq, c, s);
        float2 np, nq;
        np.x = c * gp.x - s * gq.x; nq.x = s * gp.x + c * gq.x;
        np.y = c * gp.y - s * gq.y; nq.y = s * gp.y + c * gq.y;
        *(float2*)(G + pb) = np;
        *(float2*)(G + qb) = nq;
        if (sub == 0) {
          float cs2 = 2.f * c * s * d, cc = c * c, ss = s * s;
          nrm[p] = cc * dpp - cs2 + ss * dqq;
          nrm[q] = ss * dpp + cs2 + cc * dqq;
        }
      }
    }
    if (!anyact) break;
  }
  __syncthreads();
}

__launch_bounds__(64)
__global__ void spdnet_kernel(const float* __restrict__ x,
                              const float* __restrict__ w1,
                              const float* __restrict__ w2,
                              const float* __restrict__ w3,
                              const float* __restrict__ fcw,
                              float* __restrict__ out,
                              int B) {
  const int b    = blockIdx.x;
  const int lane = threadIdx.x;

  // R0: x -> L -> G (32 cols x 36) -> M2 (16 cols x 20) + w3s@1024(80)
  // R1: w1 (rows, stride 36) -> w2s [0..576) + Z @576 (32x20) -> Y@0(64) + X3@64(16)
  __shared__ float R0[1152];
  __shared__ float R1[1216];
  __shared__ float NRM[32];

  const float* xb = x + (size_t)b * 1024;
  const int kc = lane >> 1, h = lane & 1, hb = h * 16;

  // ---- stage x -> R0, w1 -> R1 (both row-major, stride 36) ----
  #pragma unroll
  for (int t = 0; t < 4; ++t) {
    int i4 = lane + 64 * t;          // float4 index 0..255
    int r = i4 >> 3, c4 = i4 & 7;
    float4 xv = ((const float4*)xb)[i4];
    float4 wv = ((const float4*)w1)[i4];
    *(float4*)(R0 + r * 36 + 4 * c4) = xv;
    *(float4*)(R1 + r * 36 + 4 * c4) = wv;
  }
  float w3r = w3[lane];
  __syncthreads();

  // ---- L = x * w1 in registers: lane (kc,h) owns half-column kc ----
  float4 a0 = {0.f, 0.f, 0.f, 0.f}, a1 = a0, a2 = a0, a3 = a0;
  #pragma unroll
  for (int j = 0; j < 32; ++j) {
    float wv = R1[j * 36 + kc];           // w1[j][kc]
    const float* xc = R0 + j * 36 + hb;   // x[j][i] = x[i][j]
    axpy4(a0, wv, *(const float4*)(xc));
    axpy4(a1, wv, *(const float4*)(xc + 4));
    axpy4(a2, wv, *(const float4*)(xc + 8));
    axpy4(a3, wv, *(const float4*)(xc + 12));
  }
  __syncthreads();                        // all x reads done
  *(float4*)(R0 + kc * 36 + hb)      = a0;
  *(float4*)(R0 + kc * 36 + hb + 4)  = a1;
  *(float4*)(R0 + kc * 36 + hb + 8)  = a2;
  *(float4*)(R0 + kc * 36 + hb + 12) = a3;
  __syncthreads();

  // ---- X1[:,kc] = sum_k w1[k][:] * L[k][kc] ----
  float Lc[32];
  #pragma unroll
  for (int c4 = 0; c4 < 8; ++c4) {
    float4 v = *(const float4*)(R0 + kc * 36 + 4 * c4);
    Lc[4 * c4] = v.x; Lc[4 * c4 + 1] = v.y; Lc[4 * c4 + 2] = v.z; Lc[4 * c4 + 3] = v.w;
  }
  a0 = {0.f, 0.f, 0.f, 0.f}; a1 = a0; a2 = a0; a3 = a0;
  #pragma unroll
  for (int kk = 0; kk < 32; ++kk) {
    float lv = Lc[kk];
    const float* wr = R1 + kk * 36 + hb;  // w1[kk][i]
    axpy4(a0, lv, *(const float4*)(wr));
    axpy4(a1, lv, *(const float4*)(wr + 4));
    axpy4(a2, lv, *(const float4*)(wr + 8));
    axpy4(a3, lv, *(const float4*)(wr + 12));
  }
  float nv = dot4(a0, a0) + dot4(a1, a1) + dot4(a2, a2) + dot4(a3, a3);
  nv += shfl_xor_f(nv, 1);
  __syncthreads();                        // L & w1 reads done
  // write G = X1 over R0; stage w2 over dead w1
  *(float4*)(R0 + kc * 36 + hb)      = a0;
  *(float4*)(R0 + kc * 36 + hb + 4)  = a1;
  *(float4*)(R0 + kc * 36 + hb + 8)  = a2;
  *(float4*)(R0 + kc * 36 + hb + 12) = a3;
  if (h == 0) NRM[kc] = nv;
  #pragma unroll
  for (int t = 0; t < 8; ++t) {
    int idx = lane + 64 * t;
    int j = idx >> 4, a = idx & 15;
    R1[a * 36 + j] = w2[idx];             // w2 col a contiguous
  }
  __syncthreads();

  // ---- eig #1: one-sided Jacobi on G (n=32) ----
  jac32(R0, NRM, lane);

  // ---- Z[:,k] = (w2^T g_k) * sqrt(mu)/lam, Z @ R1+576 stride 20 ----
  {
    float g[16];
    #pragma unroll
    for (int c = 0; c < 4; ++c) {
      float4 v = *(const float4*)(R0 + kc * 36 + hb + 4 * c);
      g[4 * c] = v.x; g[4 * c + 1] = v.y; g[4 * c + 2] = v.z; g[4 * c + 3] = v.w;
    }
    float dpp = 0.f;
    #pragma unroll
    for (int i = 0; i < 16; ++i) dpp += g[i] * g[i];
    dpp += shfl_xor_f(dpp, 1);
    float lam = __builtin_amdgcn_sqrtf(dpp);
    float mu  = fmaxf(lam, 1e-4f);
    float sc  = __builtin_amdgcn_sqrtf(mu) * __builtin_amdgcn_rcpf(fmaxf(lam, 1e-30f));
    #pragma unroll
    for (int a = 0; a < 16; ++a) {
      const float* wr = R1 + a * 36 + hb;
      float part = 0.f;
      #pragma unroll
      for (int c = 0; c < 4; ++c) {
        float4 wv = *(const float4*)(wr + 4 * c);
        part += g[4 * c] * wv.x + g[4 * c + 1] * wv.y + g[4 * c + 2] * wv.z + g[4 * c + 3] * wv.w;
      }
      part += shfl_xor_f(part, 1);
      if (h == 0) R1[576 + kc * 20 + a] = part * sc;
    }
  }
  __syncthreads();

  // ---- M2 = Z Z^T (16x16) into R0 stride 20; stage w3 @ R0+1024 ----
  {
    const int a = lane & 15, b0i = (lane >> 4) * 4;
    float m0 = 0.f, m1 = 0.f, m2 = 0.f, m3 = 0.f;
    #pragma unroll
    for (int kk = 0; kk < 32; ++kk) {
      float za = R1[576 + kk * 20 + a];
      float4 zb = *(const float4*)(R1 + 576 + kk * 20 + b0i);
      m0 += za * zb.x; m1 += za * zb.y; m2 += za * zb.z; m3 += za * zb.w;
    }
    R0[(b0i + 0) * 20 + a] = m0;
    R0[(b0i + 1) * 20 + a] = m1;
    R0[(b0i + 2) * 20 + a] = m2;
    R0[(b0i + 3) * 20 + a] = m3;
    R0[1024 + (lane & 3) * 20 + (lane >> 2)] = w3r;   // w3 col-major
  }
  __syncthreads();

  // ---- norms of M2 columns ----
  if (lane < 32) {
    int cc = lane >> 1;
    float4 v0 = *(const float4*)(R0 + cc * 20 + 8 * h);
    float4 v1 = *(const float4*)(R0 + cc * 20 + 8 * h + 4);
    float n2 = dot4(v0, v0) + dot4(v1, v1);
    n2 += shfl_xor_f(n2, 1);
    if (h == 0) NRM[cc] = n2;
  }
  __syncthreads();

  // ---- eig #2: one-sided Jacobi on M2 (n=16) ----
  jac16(R0, NRM, lane);

  // ---- Y[a][k] = (w3_col_a . g2_k) * sqrt(mu2)/lam2, Y @ R1[0..64) ----
  {
    const int k3 = (lane >> 2) & 15, a3 = lane & 3;
    float dpp2 = 0.f, dotv = 0.f;
    #pragma unroll
    for (int c = 0; c < 4; ++c) {
      float4 gv = *(const float4*)(R0 + k3 * 20 + 4 * c);
      float4 wv = *(const float4*)(R0 + 1024 + a3 * 20 + 4 * c);
      dpp2 += dot4(gv, gv);
      dotv += dot4(gv, wv);
    }
    float lam2 = __builtin_amdgcn_sqrtf(dpp2);
    float mu2  = fmaxf(lam2, 1e-4f);
    float sc2  = __builtin_amdgcn_sqrtf(mu2) * __builtin_amdgcn_rcpf(fmaxf(lam2, 1e-30f));
    __syncthreads();                      // M2/w3 reads done before Y write (R1 dead)
    R1[k3 * 4 + a3] = dotv * sc2;         // Y, k-major stride 4
  }
  __syncthreads();
  if (lane < 16) {
    int a = lane >> 2, b2 = lane & 3;
    float s = 0.f;
    #pragma unroll
    for (int kk = 0; kk < 16; ++kk)
      s += R1[kk * 4 + a] * R1[kk * 4 + b2];
    R1[64 + lane] = s;                    // X3
  }
  __syncthreads();

  // ---- stage 3: serial 4x4 two-sided Jacobi + LogEig + fc + log_softmax ----
  if (lane == 0) {
    float Am[4][4], V[4][4];
    float maxd = 0.f;
    #pragma unroll
    for (int i = 0; i < 4; ++i) {
      #pragma unroll
      for (int j = 0; j < 4; ++j) {
        Am[i][j] = R1[64 + i * 4 + j];
        V[i][j] = (i == j) ? 1.f : 0.f;
      }
      maxd = fmaxf(maxd, fabsf(Am[i][i]));
    }
    float tol3 = 1e-7f * maxd;
    for (int sw = 0; sw < MAXSW4; ++sw) {
      bool any = false;
      #pragma unroll
      for (int p = 0; p < 3; ++p) {
        #pragma unroll
        for (int q = p + 1; q < 4; ++q) {
          float apq = Am[p][q];
          if (fabsf(apq) > tol3) {
            any = true;
            float c, sv;
            rot_cs(apq, Am[p][p], Am[q][q], c, sv);
            #pragma unroll
            for (int j = 0; j < 4; ++j) {
              float ap = Am[p][j], aq = Am[q][j];
              Am[p][j] = c * ap - sv * aq;
              Am[q][j] = sv * ap + c * aq;
            }
            #pragma unroll
            for (int i = 0; i < 4; ++i) {
              float ap = Am[i][p], aq = Am[i][q];
              Am[i][p] = c * ap - sv * aq;
              Am[i][q] = sv * ap + c * aq;
              float up = V[i][p], uq = V[i][q];
              V[i][p] = c * up - sv * uq;
              V[i][q] = sv * up + c * uq;
            }
          }
        }
      }
      if (!any) break;
    }
    float lm[4];
    #pragma unroll
    for (int i = 0; i < 4; ++i) lm[i] = logf(fmaxf(Am[i][i], 1e-10f));
    float feat[16];
    #pragma unroll
    for (int i = 0; i < 4; ++i)
      #pragma unroll
      for (int j = 0; j < 4; ++j) {
        float acc2 = 0.f;
        #pragma unroll
        for (int kk = 0; kk < 4; ++kk) acc2 += V[i][kk] * lm[kk] * V[j][kk];
        feat[i * 4 + j] = acc2;
      }
    float z0 = 0.f, z1 = 0.f;
    #pragma unroll
    for (int f = 0; f < 16; ++f) {
      z0 += feat[f] * fcw[f * 2 + 0];
      z1 += feat[f] * fcw[f * 2 + 1];
    }
    float mx = fmaxf(z0, z1);
    float lse = mx + logf(expf(z0 - mx) + expf(z1 - mx));
    out[b * 2 + 0] = z0 - lse;
    out[b * 2 + 1] = z1 - lse;
    float* fo = out + (size_t)2 * B + (size_t)b * 16;
    #pragma unroll
    for (int f = 0; f < 16; ++f) fo[f] = feat[f];
  }
}

extern "C" void kernel_launch(void* const* d_in, const int* in_sizes, int n_in,
                              void* d_out, int out_size, void* d_ws, size_t ws_size,
                              hipStream_t stream) {
  (void)n_in; (void)d_ws; (void)ws_size; (void)out_size;
  const float* x   = (const float*)d_in[0];
  const float* w1  = (const float*)d_in[1];
  const float* w2  = (const float*)d_in[2];
  const float* w3  = (const float*)d_in[3];
  const float* fcw = (const float*)d_in[4];
  float* out = (float*)d_out;
  int B = in_sizes[0] / 1024;
  spdnet_kernel<<<B, 64, 0, stream>>>(x, w1, w2, w3, fcw, out, B);
}

// Round 8
// 1897.884 us; speedup vs baseline: 1.4460x; 1.1762x over previous
//
#include <hip/hip_runtime.h>
#include <math.h>

// SPDNet forward, one wave (64 lanes) per batch element, one-sided (Hestenes)
// Jacobi. Columns orthogonalized in place in LDS; eigenvalues = column norms,
// eigenvectors = normalized columns. All column traffic ds_read/write_b128.
//
// Round 8: bank-aware pair-group <-> lane remap. Tournament group k handles
// column p = istar+k; with stride-36 columns, bank window starts at 4*(p%8).
// Assign quad kq to group k = (kq&8)|bitrev3(kq&7) so each aligned 8/16-lane
// phase handles p's spread mod 8 (stride 4/2) -> bank windows tile the 32
// banks instead of overlapping. Pure relabeling: rotations within a round are
// disjoint => bitwise-identical results. jac16 likewise (5*dk=4 mod 8 -> dk=4
// map), and its 8-lane reduction uses DPP quad_perm + row_half_mirror (VALU
// pipe) instead of ds_swizzle.
//
// LDS: R0[1152] matrix buffer (stride 36 / 20), R1[1216] weights+Z, NRM[32].
// ~9.6 KB/wave -> ~16 waves/CU.

#define MAXSW32 8
#define MAXSW16 8
#define MAXSW4  8
#define JTOL2   1e-12f

// Compiler-only memory fence (single-wave block: LDS is HW-ordered per wave).
#define CFENCE() asm volatile("" ::: "memory")

__device__ __forceinline__ float shfl_xor_f(float v, int m) { return __shfl_xor(v, m, 64); }
__device__ __forceinline__ float dot4(float4 a, float4 b) {
  return a.x * b.x + a.y * b.y + a.z * b.z + a.w * b.w;
}
__device__ __forceinline__ void axpy4(float4& a, float xv, float4 w) {
  a.x += xv * w.x; a.y += xv * w.y; a.z += xv * w.z; a.w += xv * w.w;
}

// DPP lane-exchange adds (VALU pipe, no DS traffic).
__device__ __forceinline__ float dpp_add_xor1(float d) {
  return d + __int_as_float(__builtin_amdgcn_mov_dpp(__float_as_int(d), 0xB1, 0xF, 0xF, true));
}
__device__ __forceinline__ float dpp_add_xor2(float d) {
  return d + __int_as_float(__builtin_amdgcn_mov_dpp(__float_as_int(d), 0x4E, 0xF, 0xF, true));
}
__device__ __forceinline__ float dpp_add_halfmirror(float d) {  // completes 8-lane sum
  return d + __int_as_float(__builtin_amdgcn_mov_dpp(__float_as_int(d), 0x141, 0xF, 0xF, true));
}

// Jacobi rotation from off-diag dot d and norms dpp,dqq. Divide-free.
__device__ __forceinline__ void rot_cs(float d, float dpp, float dqq,
                                       float& c, float& s) {
  float tau = 0.5f * (dqq - dpp);
  float r   = __builtin_amdgcn_sqrtf(fmaf(tau, tau, d * d));
  float den = fabsf(tau) + r;
  float tnum = __uint_as_float(__float_as_uint(d) ^
                               (__float_as_uint(tau) & 0x80000000u));
  float t = tnum * __builtin_amdgcn_rcpf(den);
  c = __builtin_amdgcn_rsqf(fmaf(t, t, 1.f));
  s = t * c;
}

// One-sided Jacobi, n=32, column stride 36. 16 pairs x 4 lanes.
__device__ __forceinline__ void jac32(float* __restrict__ G, float* __restrict__ nrm,
                                      int lane) {
  const int kq  = lane >> 2, sub = lane & 3;
  // bank-aware group relabel: 0,4,2,6,1,5,3,7 within each 8 (bitrev3)
  const int k = (kq & 8) | ((kq & 1) << 2) | (kq & 2) | ((kq & 4) >> 2);
  const int o0 = 4 * sub, o1 = 4 * sub + 16;
  int pp = (k == 0) ? 31 : k;
  int qq = (k == 0) ? 0 : (31 - k);
  for (int sw = 0; sw < MAXSW32; ++sw) {
    bool anyact = false;
    for (int r = 0; r < 31; ++r) {
      CFENCE();                       // order vs previous round's LDS writes
      const int p = pp, q = qq;
      if (k != 0) { pp += 16; if (pp >= 31) pp -= 31; }
      qq += 16; if (qq >= 31) qq -= 31;
      const int pb = p * 36, qb = q * 36;
      float dpp = nrm[p], dqq = nrm[q];
      float4 gp0 = *(const float4*)(G + pb + o0);
      float4 gp1 = *(const float4*)(G + pb + o1);
      float4 gq0 = *(const float4*)(G + qb + o0);
      float4 gq1 = *(const float4*)(G + qb + o1);
      float d = dot4(gp0, gq0) + dot4(gp1, gq1);
      d = dpp_add_xor1(d);
      d = dpp_add_xor2(d);
      bool active = (d * d > JTOL2 * dpp * dqq);
      if (__ballot(active) == 0ull) continue;
      anyact = true;
      if (active) {
        float c, s;
        rot_cs(d, dpp, dqq, c, s);
        float4 np0, np1, nq0, nq1;
        np0.x = c * gp0.x - s * gq0.x; nq0.x = s * gp0.x + c * gq0.x;
        np0.y = c * gp0.y - s * gq0.y; nq0.y = s * gp0.y + c * gq0.y;
        np0.z = c * gp0.z - s * gq0.z; nq0.z = s * gp0.z + c * gq0.z;
        np0.w = c * gp0.w - s * gq0.w; nq0.w = s * gp0.w + c * gq0.w;
        np1.x = c * gp1.x - s * gq1.x; nq1.x = s * gp1.x + c * gq1.x;
        np1.y = c * gp1.y - s * gq1.y; nq1.y = s * gp1.y + c * gq1.y;
        np1.z = c * gp1.z - s * gq1.z; nq1.z = s * gp1.z + c * gq1.z;
        np1.w = c * gp1.w - s * gq1.w; nq1.w = s * gp1.w + c * gq1.w;
        *(float4*)(G + pb + o0) = np0;
        *(float4*)(G + pb + o1) = np1;
        *(float4*)(G + qb + o0) = nq0;
        *(float4*)(G + qb + o1) = nq1;
        if (sub == 0) {
          float cs2 = 2.f * c * s * d, cc = c * c, ss = s * s;
          nrm[p] = cc * dpp - cs2 + ss * dqq;
          nrm[q] = ss * dpp + cs2 + cc * dqq;
        }
      }
    }
    if (!anyact) break;
  }
  __syncthreads();
}

// One-sided Jacobi, n=16, column stride 20. 8 pairs x 8 lanes.
__device__ __forceinline__ void jac16(float* __restrict__ G, float* __restrict__ nrm,
                                      int lane) {
  const int kq = lane >> 3, sub = lane & 7;
  // bank-aware relabel: adjacent group-pairs spaced 4 (5*4 = 4 mod 8)
  const int k = (kq >> 1) | ((kq & 1) << 2);   // 0,4,1,5,2,6,3,7
  const int o = 2 * sub;
  int pp = (k == 0) ? 15 : k;
  int qq = (k == 0) ? 0 : (15 - k);
  for (int sw = 0; sw < MAXSW16; ++sw) {
    bool anyact = false;
    for (int r = 0; r < 15; ++r) {
      CFENCE();
      const int p = pp, q = qq;
      if (k != 0) { pp += 8; if (pp >= 15) pp -= 15; }
      qq += 8; if (qq >= 15) qq -= 15;
      const int pb = p * 20 + o, qb = q * 20 + o;
      float dpp = nrm[p], dqq = nrm[q];
      float2 gp = *(const float2*)(G + pb);
      float2 gq = *(const float2*)(G + qb);
      float d = gp.x * gq.x + gp.y * gq.y;
      d = dpp_add_xor1(d);
      d = dpp_add_xor2(d);
      d = dpp_add_halfmirror(d);      // sum over the 8-lane group, VALU pipe
      bool active = (d * d > JTOL2 * dpp * dqq);
      if (__ballot(active) == 0ull) continue;
      anyact = true;
      if (active) {
        float c, s;
        rot_cs(d, dpp, dqq, c, s);
        float2 np, nq;
        np.x = c * gp.x - s * gq.x; nq.x = s * gp.x + c * gq.x;
        np.y = c * gp.y - s * gq.y; nq.y = s * gp.y + c * gq.y;
        *(float2*)(G + pb) = np;
        *(float2*)(G + qb) = nq;
        if (sub == 0) {
          float cs2 = 2.f * c * s * d, cc = c * c, ss = s * s;
          nrm[p] = cc * dpp - cs2 + ss * dqq;
          nrm[q] = ss * dpp + cs2 + cc * dqq;
        }
      }
    }
    if (!anyact) break;
  }
  __syncthreads();
}

__launch_bounds__(64)
__global__ void spdnet_kernel(const float* __restrict__ x,
                              const float* __restrict__ w1,
                              const float* __restrict__ w2,
                              const float* __restrict__ w3,
                              const float* __restrict__ fcw,
                              float* __restrict__ out,
                              int B) {
  const int b    = blockIdx.x;
  const int lane = threadIdx.x;

  // R0: x -> L -> G (32 cols x 36) -> M2 (16 cols x 20) + w3s@1024(80)
  // R1: w1 (rows, stride 36) -> w2s [0..576) + Z @576 (32x20) -> Y@0(64) + X3@64(16)
  __shared__ float R0[1152];
  __shared__ float R1[1216];
  __shared__ float NRM[32];

  const float* xb = x + (size_t)b * 1024;
  const int kc = lane >> 1, h = lane & 1, hb = h * 16;

  // ---- stage x -> R0, w1 -> R1 (both row-major, stride 36) ----
  #pragma unroll
  for (int t = 0; t < 4; ++t) {
    int i4 = lane + 64 * t;          // float4 index 0..255
    int r = i4 >> 3, c4 = i4 & 7;
    float4 xv = ((const float4*)xb)[i4];
    float4 wv = ((const float4*)w1)[i4];
    *(float4*)(R0 + r * 36 + 4 * c4) = xv;
    *(float4*)(R1 + r * 36 + 4 * c4) = wv;
  }
  float w3r = w3[lane];
  __syncthreads();

  // ---- L = x * w1 in registers: lane (kc,h) owns half-column kc ----
  float4 a0 = {0.f, 0.f, 0.f, 0.f}, a1 = a0, a2 = a0, a3 = a0;
  #pragma unroll
  for (int j = 0; j < 32; ++j) {
    float wv = R1[j * 36 + kc];           // w1[j][kc]
    const float* xc = R0 + j * 36 + hb;   // x[j][i] = x[i][j]
    axpy4(a0, wv, *(const float4*)(xc));
    axpy4(a1, wv, *(const float4*)(xc + 4));
    axpy4(a2, wv, *(const float4*)(xc + 8));
    axpy4(a3, wv, *(const float4*)(xc + 12));
  }
  __syncthreads();                        // all x reads done
  *(float4*)(R0 + kc * 36 + hb)      = a0;
  *(float4*)(R0 + kc * 36 + hb + 4)  = a1;
  *(float4*)(R0 + kc * 36 + hb + 8)  = a2;
  *(float4*)(R0 + kc * 36 + hb + 12) = a3;
  __syncthreads();

  // ---- X1[:,kc] = sum_k w1[k][:] * L[k][kc] ----
  float Lc[32];
  #pragma unroll
  for (int c4 = 0; c4 < 8; ++c4) {
    float4 v = *(const float4*)(R0 + kc * 36 + 4 * c4);
    Lc[4 * c4] = v.x; Lc[4 * c4 + 1] = v.y; Lc[4 * c4 + 2] = v.z; Lc[4 * c4 + 3] = v.w;
  }
  a0 = {0.f, 0.f, 0.f, 0.f}; a1 = a0; a2 = a0; a3 = a0;
  #pragma unroll
  for (int kk = 0; kk < 32; ++kk) {
    float lv = Lc[kk];
    const float* wr = R1 + kk * 36 + hb;  // w1[kk][i]
    axpy4(a0, lv, *(const float4*)(wr));
    axpy4(a1, lv, *(const float4*)(wr + 4));
    axpy4(a2, lv, *(const float4*)(wr + 8));
    axpy4(a3, lv, *(const float4*)(wr + 12));
  }
  float nv = dot4(a0, a0) + dot4(a1, a1) + dot4(a2, a2) + dot4(a3, a3);
  nv += shfl_xor_f(nv, 1);
  __syncthreads();                        // L & w1 reads done
  // write G = X1 over R0; stage w2 over dead w1
  *(float4*)(R0 + kc * 36 + hb)      = a0;
  *(float4*)(R0 + kc * 36 + hb + 4)  = a1;
  *(float4*)(R0 + kc * 36 + hb + 8)  = a2;
  *(float4*)(R0 + kc * 36 + hb + 12) = a3;
  if (h == 0) NRM[kc] = nv;
  #pragma unroll
  for (int t = 0; t < 8; ++t) {
    int idx = lane + 64 * t;
    int j = idx >> 4, a = idx & 15;
    R1[a * 36 + j] = w2[idx];             // w2 col a contiguous
  }
  __syncthreads();

  // ---- eig #1: one-sided Jacobi on G (n=32) ----
  jac32(R0, NRM, lane);

  // ---- Z[:,k] = (w2^T g_k) * sqrt(mu)/lam, Z @ R1+576 stride 20 ----
  {
    float g[16];
    #pragma unroll
    for (int c = 0; c < 4; ++c) {
      float4 v = *(const float4*)(R0 + kc * 36 + hb + 4 * c);
      g[4 * c] = v.x; g[4 * c + 1] = v.y; g[4 * c + 2] = v.z; g[4 * c + 3] = v.w;
    }
    float dpp = 0.f;
    #pragma unroll
    for (int i = 0; i < 16; ++i) dpp += g[i] * g[i];
    dpp += shfl_xor_f(dpp, 1);
    float lam = __builtin_amdgcn_sqrtf(dpp);
    float mu  = fmaxf(lam, 1e-4f);
    float sc  = __builtin_amdgcn_sqrtf(mu) * __builtin_amdgcn_rcpf(fmaxf(lam, 1e-30f));
    #pragma unroll
    for (int a = 0; a < 16; ++a) {
      const float* wr = R1 + a * 36 + hb;
      float part = 0.f;
      #pragma unroll
      for (int c = 0; c < 4; ++c) {
        float4 wv = *(const float4*)(wr + 4 * c);
        part += g[4 * c] * wv.x + g[4 * c + 1] * wv.y + g[4 * c + 2] * wv.z + g[4 * c + 3] * wv.w;
      }
      part = dpp_add_xor1(part);
      if (h == 0) R1[576 + kc * 20 + a] = part * sc;
    }
  }
  __syncthreads();

  // ---- M2 = Z Z^T (16x16) into R0 stride 20; stage w3 @ R0+1024 ----
  {
    const int a = lane & 15, b0i = (lane >> 4) * 4;
    float m0 = 0.f, m1 = 0.f, m2 = 0.f, m3 = 0.f;
    #pragma unroll
    for (int kk = 0; kk < 32; ++kk) {
      float za = R1[576 + kk * 20 + a];
      float4 zb = *(const float4*)(R1 + 576 + kk * 20 + b0i);
      m0 += za * zb.x; m1 += za * zb.y; m2 += za * zb.z; m3 += za * zb.w;
    }
    R0[(b0i + 0) * 20 + a] = m0;
    R0[(b0i + 1) * 20 + a] = m1;
    R0[(b0i + 2) * 20 + a] = m2;
    R0[(b0i + 3) * 20 + a] = m3;
    R0[1024 + (lane & 3) * 20 + (lane >> 2)] = w3r;   // w3 col-major
  }
  __syncthreads();

  // ---- norms of M2 columns ----
  if (lane < 32) {
    int cc = lane >> 1;
    float4 v0 = *(const float4*)(R0 + cc * 20 + 8 * h);
    float4 v1 = *(const float4*)(R0 + cc * 20 + 8 * h + 4);
    float n2 = dot4(v0, v0) + dot4(v1, v1);
    n2 += shfl_xor_f(n2, 1);
    if (h == 0) NRM[cc] = n2;
  }
  __syncthreads();

  // ---- eig #2: one-sided Jacobi on M2 (n=16) ----
  jac16(R0, NRM, lane);

  // ---- Y[a][k] = (w3_col_a . g2_k) * sqrt(mu2)/lam2, Y @ R1[0..64) ----
  {
    const int k3 = (lane >> 2) & 15, a3 = lane & 3;
    float dpp2 = 0.f, dotv = 0.f;
    #pragma unroll
    for (int c = 0; c < 4; ++c) {
      float4 gv = *(const float4*)(R0 + k3 * 20 + 4 * c);
      float4 wv = *(const float4*)(R0 + 1024 + a3 * 20 + 4 * c);
      dpp2 += dot4(gv, gv);
      dotv += dot4(gv, wv);
    }
    float lam2 = __builtin_amdgcn_sqrtf(dpp2);
    float mu2  = fmaxf(lam2, 1e-4f);
    float sc2  = __builtin_amdgcn_sqrtf(mu2) * __builtin_amdgcn_rcpf(fmaxf(lam2, 1e-30f));
    __syncthreads();                      // M2/w3 reads done before Y write (R1 dead)
    R1[k3 * 4 + a3] = dotv * sc2;         // Y, k-major stride 4
  }
  __syncthreads();
  if (lane < 16) {
    int a = lane >> 2, b2 = lane & 3;
    float s = 0.f;
    #pragma unroll
    for (int kk = 0; kk < 16; ++kk)
      s += R1[kk * 4 + a] * R1[kk * 4 + b2];
    R1[64 + lane] = s;                    // X3
  }
  __syncthreads();

  // ---- stage 3: serial 4x4 two-sided Jacobi + LogEig + fc + log_softmax ----
  if (lane == 0) {
    float Am[4][4], V[4][4];
    float maxd = 0.f;
    #pragma unroll
    for (int i = 0; i < 4; ++i) {
      #pragma unroll
      for (int j = 0; j < 4; ++j) {
        Am[i][j] = R1[64 + i * 4 + j];
        V[i][j] = (i == j) ? 1.f : 0.f;
      }
      maxd = fmaxf(maxd, fabsf(Am[i][i]));
    }
    float tol3 = 1e-7f * maxd;
    for (int sw = 0; sw < MAXSW4; ++sw) {
      bool any = false;
      #pragma unroll
      for (int p = 0; p < 3; ++p) {
        #pragma unroll
        for (int q = p + 1; q < 4; ++q) {
          float apq = Am[p][q];
          if (fabsf(apq) > tol3) {
            any = true;
            float c, sv;
            rot_cs(apq, Am[p][p], Am[q][q], c, sv);
            #pragma unroll
            for (int j = 0; j < 4; ++j) {
              float ap = Am[p][j], aq = Am[q][j];
              Am[p][j] = c * ap - sv * aq;
              Am[q][j] = sv * ap + c * aq;
            }
            #pragma unroll
            for (int i = 0; i < 4; ++i) {
              float ap = Am[i][p], aq = Am[i][q];
              Am[i][p] = c * ap - sv * aq;
              Am[i][q] = sv * ap + c * aq;
              float up = V[i][p], uq = V[i][q];
              V[i][p] = c * up - sv * uq;
              V[i][q] = sv * up + c * uq;
            }
          }
        }
      }
      if (!any) break;
    }
    float lm[4];
    #pragma unroll
    for (int i = 0; i < 4; ++i) lm[i] = logf(fmaxf(Am[i][i], 1e-10f));
    float feat[16];
    #pragma unroll
    for (int i = 0; i < 4; ++i)
      #pragma unroll
      for (int j = 0; j < 4; ++j) {
        float acc2 = 0.f;
        #pragma unroll
        for (int kk = 0; kk < 4; ++kk) acc2 += V[i][kk] * lm[kk] * V[j][kk];
        feat[i * 4 + j] = acc2;
      }
    float z0 = 0.f, z1 = 0.f;
    #pragma unroll
    for (int f = 0; f < 16; ++f) {
      z0 += feat[f] * fcw[f * 2 + 0];
      z1 += feat[f] * fcw[f * 2 + 1];
    }
    float mx = fmaxf(z0, z1);
    float lse = mx + logf(expf(z0 - mx) + expf(z1 - mx));
    out[b * 2 + 0] = z0 - lse;
    out[b * 2 + 1] = z1 - lse;
    float* fo = out + (size_t)2 * B + (size_t)b * 16;
    #pragma unroll
    for (int f = 0; f < 16; ++f) fo[f] = feat[f];
  }
}

extern "C" void kernel_launch(void* const* d_in, const int* in_sizes, int n_in,
                              void* d_out, int out_size, void* d_ws, size_t ws_size,
                              hipStream_t stream) {
  (void)n_in; (void)d_ws; (void)ws_size; (void)out_size;
  const float* x   = (const float*)d_in[0];
  const float* w1  = (const float*)d_in[1];
  const float* w2  = (const float*)d_in[2];
  const float* w3  = (const float*)d_in[3];
  const float* fcw = (const float*)d_in[4];
  float* out = (float*)d_out;
  int B = in_sizes[0] / 1024;
  spdnet_kernel<<<B, 64, 0, stream>>>(x, w1, w2, w3, fcw, out, B);
}